// Round 2
// baseline (494.507 us; speedup 1.0000x reference)
//
#include <hip/hip_runtime.h>
#include <hip/hip_bf16.h>
#include <stdint.h>

// B=16, TH=TS=HS=WS=1024
// res[b,i,o] = sum_j softmax_j(hp[b,i,:].sp[b,j,:]) * hp[b,j,o]
// hp = h*Wh^T + bh ; sp = s*Ws^T + bs
// Precision: GEMM1/2/3 use split-bf16 (hi+lo) with 3 cross-term MFMAs -> ~f32.

typedef __attribute__((ext_vector_type(8))) short short8;     // 8 bf16 (4 VGPR)
typedef __attribute__((ext_vector_type(4))) float floatx4;    // MFMA acc
typedef __attribute__((ext_vector_type(4))) unsigned short ushortx4;

__device__ __forceinline__ unsigned short f2b(float f) {
    unsigned u = __float_as_uint(f);
    u += 0x7FFFu + ((u >> 16) & 1u);   // RNE (inputs finite)
    return (unsigned short)(u >> 16);
}
__device__ __forceinline__ float b2f(unsigned short u) {
    return __uint_as_float(((unsigned)u) << 16);
}

__device__ __forceinline__ void gl2lds16(const void* g, void* l) {
    __builtin_amdgcn_global_load_lds(
        (const __attribute__((address_space(1))) uint32_t*)(uintptr_t)g,
        (__attribute__((address_space(3))) uint32_t*)(uintptr_t)l,
        16, 0, 0);
}

#define TILE 128
#define BK 32

// C[r][c] = sum_k A[r][k]*B[c][k] (+bias[c]); operands K-major (B^T GEMM).
// SPLIT: A,B given as (hi,lo) bf16 pairs; acc += Ah*Bh + Ah*Bl + Al*Bh.
// Outputs: WF32 -> f32 Cf; WHILO -> bf16 split pair (Chi,Clo); WB16T -> bf16
// transposed per-1024-row batch (for PV's B operand).
template<int SPLIT, int WF32, int WHILO, int WB16T>
__global__ void gemm_bt(const unsigned short* __restrict__ Ah,
                        const unsigned short* __restrict__ Al,
                        const unsigned short* __restrict__ Bh,
                        const unsigned short* __restrict__ Bl,
                        const float* __restrict__ bias,
                        float* __restrict__ Cf,
                        unsigned short* __restrict__ Chi,
                        unsigned short* __restrict__ Clo,
                        unsigned short* __restrict__ CbT,
                        int K, int lda, int ldb, int N,
                        long aBatch, long bBatch, long cfBatch,
                        int ldcf)
{
    constexpr int NS = SPLIT ? 2 : 1;
    __shared__ __attribute__((aligned(16))) unsigned short At[2][NS][TILE * BK];
    __shared__ __attribute__((aligned(16))) unsigned short Bt[2][NS][TILE * BK];

    const int tid  = threadIdx.x;
    const int wave = tid >> 6;
    const int lane = tid & 63;
    const int wr = wave >> 1, wc = wave & 1;       // wave -> 64x64 quadrant
    const int lg = lane >> 4, lr = lane & 15;      // k-group / row-in-16

    const long batch = blockIdx.z;
    const int row0 = blockIdx.x * TILE;
    const int col0 = blockIdx.y * TILE;

    const unsigned short* Asrc[2] = { Ah + batch * aBatch, SPLIT ? Al + batch * aBatch : nullptr };
    const unsigned short* Bsrc[2] = { Bh + batch * bBatch, SPLIT ? Bl + batch * bBatch : nullptr };

    floatx4 acc[4][4];
#pragma unroll
    for (int m = 0; m < 4; ++m)
#pragma unroll
        for (int n = 0; n < 4; ++n)
            acc[m][n] = (floatx4){0.f, 0.f, 0.f, 0.f};

    const int NT = K / BK;

    auto stage = [&](int buf, int kk) {
#pragma unroll
        for (int hl = 0; hl < NS; ++hl) {
#pragma unroll
            for (int i = 0; i < 2; ++i) {
                const int o = i * 4096 + tid * 16;     // linear byte off in 8KB tile
                const int row = o >> 6;                // 64B per row (32 bf16)
                const int colb = o & 63;
                gl2lds16((const char*)Asrc[hl] + (long)(row0 + row) * ((long)lda * 2) + (long)kk * 2 + colb,
                         (char*)&At[buf][hl][0] + i * 4096 + wave * 1024);
            }
#pragma unroll
            for (int i = 0; i < 2; ++i) {
                const int o = i * 4096 + tid * 16;
                const int row = o >> 6;
                const int colb = o & 63;
                gl2lds16((const char*)Bsrc[hl] + (long)(col0 + row) * ((long)ldb * 2) + (long)kk * 2 + colb,
                         (char*)&Bt[buf][hl][0] + i * 4096 + wave * 1024);
            }
        }
    };

    stage(0, 0);
    int cur = 0;
    for (int kt = 0; kt < NT; ++kt) {
        __syncthreads();                            // buf[cur] ready (drains vmcnt)
        if (kt + 1 < NT) stage(cur ^ 1, (kt + 1) * BK);

        short8 af[NS][4], bfr[NS][4];
#pragma unroll
        for (int hl = 0; hl < NS; ++hl) {
#pragma unroll
            for (int m = 0; m < 4; ++m) {
                const int r = wr * 64 + m * 16 + lr;
                af[hl][m] = *(const short8*)&At[cur][hl][r * BK + lg * 8];
            }
#pragma unroll
            for (int n = 0; n < 4; ++n) {
                const int c = wc * 64 + n * 16 + lr;
                bfr[hl][n] = *(const short8*)&Bt[cur][hl][c * BK + lg * 8];
            }
        }
#pragma unroll
        for (int m = 0; m < 4; ++m)
#pragma unroll
            for (int n = 0; n < 4; ++n) {
                acc[m][n] = __builtin_amdgcn_mfma_f32_16x16x32_bf16(af[0][m], bfr[0][n], acc[m][n], 0, 0, 0);
                if constexpr (SPLIT) {
                    acc[m][n] = __builtin_amdgcn_mfma_f32_16x16x32_bf16(af[0][m], bfr[1][n], acc[m][n], 0, 0, 0);
                    acc[m][n] = __builtin_amdgcn_mfma_f32_16x16x32_bf16(af[1][m], bfr[0][n], acc[m][n], 0, 0, 0);
                }
            }
        cur ^= 1;
    }

    // epilogue: D frag layout col=lane&15, row=(lane>>4)*4+j
#pragma unroll
    for (int m = 0; m < 4; ++m) {
        const int gr0 = row0 + wr * 64 + m * 16 + lg * 4;
#pragma unroll
        for (int n = 0; n < 4; ++n) {
            const int gc = col0 + wc * 64 + n * 16 + lr;
            floatx4 v = acc[m][n];
            if (bias) {
                const float b = bias[gc];
                v[0] += b; v[1] += b; v[2] += b; v[3] += b;
            }
            if (WF32) {
                float* p = Cf + batch * cfBatch + (long)gr0 * ldcf + gc;
#pragma unroll
                for (int j = 0; j < 4; ++j) p[(long)j * ldcf] = v[j];
            }
            if (WHILO) {
#pragma unroll
                for (int j = 0; j < 4; ++j) {
                    const unsigned short hi = f2b(v[j]);
                    Chi[(long)(gr0 + j) * N + gc] = hi;
                    Clo[(long)(gr0 + j) * N + gc] = f2b(v[j] - b2f(hi));
                }
            }
            if (WB16T) {
                const int b2 = gr0 >> 10;
                const int t  = gr0 & 1023;
                ushortx4 pk = { f2b(v[0]), f2b(v[1]), f2b(v[2]), f2b(v[3]) };
                *(ushortx4*)&CbT[(long)b2 * 1048576 + (long)gc * 1024 + t] = pk;
            }
        }
    }
}

// In-place: reads f32 row (1024), writes bf16 probabilities over its own first half.
__global__ void softmax_inplace(float* __restrict__ S) {
    const long r = blockIdx.x;
    float* row = S + r * 1024;
    const int tid = threadIdx.x;
    const int wave = tid >> 6, lane = tid & 63;

    float4 v = ((const float4*)row)[tid];
    float mx = fmaxf(fmaxf(v.x, v.y), fmaxf(v.z, v.w));
#pragma unroll
    for (int off = 32; off > 0; off >>= 1)
        mx = fmaxf(mx, __shfl_xor(mx, off));
    __shared__ float rmx[4], rsm[4];
    if (lane == 0) rmx[wave] = mx;
    __syncthreads();
    mx = fmaxf(fmaxf(rmx[0], rmx[1]), fmaxf(rmx[2], rmx[3]));

    float e0 = __expf(v.x - mx), e1 = __expf(v.y - mx);
    float e2 = __expf(v.z - mx), e3 = __expf(v.w - mx);
    float s = e0 + e1 + e2 + e3;
#pragma unroll
    for (int off = 32; off > 0; off >>= 1)
        s += __shfl_xor(s, off);
    if (lane == 0) rsm[wave] = s;
    __syncthreads();
    s = rsm[0] + rsm[1] + rsm[2] + rsm[3];

    const float inv = 1.0f / s;
    ushortx4 o = { f2b(e0 * inv), f2b(e1 * inv), f2b(e2 * inv), f2b(e3 * inv) };
    ((ushortx4*)((unsigned short*)S + r * 2048))[tid] = o;
}

__global__ void cvt_split(const float4* __restrict__ src,
                          ushortx4* __restrict__ hi, ushortx4* __restrict__ lo, int n4) {
    const int stride = gridDim.x * blockDim.x;
    for (int i = blockIdx.x * blockDim.x + threadIdx.x; i < n4; i += stride) {
        float4 v = src[i];
        ushortx4 h, l;
#pragma unroll
        for (int j = 0; j < 4; ++j) {
            const float x = (j == 0) ? v.x : (j == 1) ? v.y : (j == 2) ? v.z : v.w;
            const unsigned short hh = f2b(x);
            h[j] = hh;
            l[j] = f2b(x - b2f(hh));
        }
        hi[i] = h; lo[i] = l;
    }
}

extern "C" void kernel_launch(void* const* d_in, const int* in_sizes, int n_in,
                              void* d_out, int out_size, void* d_ws, size_t ws_size,
                              hipStream_t stream) {
    const float* h  = (const float*)d_in[0];
    const float* s  = (const float*)d_in[1];
    const float* Wh = (const float*)d_in[2];
    const float* bh = (const float*)d_in[3];
    const float* Ws = (const float*)d_in[4];
    const float* bs = (const float*)d_in[5];

    const long MB = 16384;   // B*TH
    const long D  = 1024;

    // workspace carve (~232 MB); region A reused: h-splits -> s-splits -> scores
    char* w = (char*)d_ws;
    unsigned short* inA_hi = (unsigned short*)w;  w += MB * D * 2;   // 32MB
    unsigned short* inA_lo = (unsigned short*)w;  w += MB * D * 2;   // 32MB
    float*          sc     = (float*)inA_hi;                          // scores alias (64MB)
    unsigned short* Whh = (unsigned short*)w;  w += D * D * 2;
    unsigned short* Whl = (unsigned short*)w;  w += D * D * 2;
    unsigned short* Wsh = (unsigned short*)w;  w += D * D * 2;
    unsigned short* Wsl = (unsigned short*)w;  w += D * D * 2;
    unsigned short* hp_hi = (unsigned short*)w;  w += MB * D * 2;
    unsigned short* hp_lo = (unsigned short*)w;  w += MB * D * 2;
    unsigned short* sp_hi = (unsigned short*)w;  w += MB * D * 2;
    unsigned short* sp_lo = (unsigned short*)w;  w += MB * D * 2;
    unsigned short* hpT   = (unsigned short*)w;  w += MB * D * 2;    // [16][o][t] bf16

    dim3 blk(256);

    cvt_split<<<512, 256, 0, stream>>>((const float4*)Wh, (ushortx4*)Whh, (ushortx4*)Whl, (int)(D * D / 4));
    cvt_split<<<512, 256, 0, stream>>>((const float4*)Ws, (ushortx4*)Wsh, (ushortx4*)Wsl, (int)(D * D / 4));

    // h -> splits; GEMM1: hp(split) = h*Wh^T + bh, also hpT bf16
    cvt_split<<<2048, 256, 0, stream>>>((const float4*)h, (ushortx4*)inA_hi, (ushortx4*)inA_lo, (int)(MB * D / 4));
    gemm_bt<1,0,1,1><<<dim3(128, 8, 1), blk, 0, stream>>>(
        inA_hi, inA_lo, Whh, Whl, bh, nullptr, hp_hi, hp_lo, hpT,
        1024, 1024, 1024, 1024, 0, 0, 0, 0);

    // s -> splits (reuse region); GEMM2: sp(split) = s*Ws^T + bs
    cvt_split<<<2048, 256, 0, stream>>>((const float4*)s, (ushortx4*)inA_hi, (ushortx4*)inA_lo, (int)(MB * D / 4));
    gemm_bt<1,0,1,0><<<dim3(128, 8, 1), blk, 0, stream>>>(
        inA_hi, inA_lo, Wsh, Wsl, bs, nullptr, sp_hi, sp_lo, nullptr,
        1024, 1024, 1024, 1024, 0, 0, 0, 0);

    // GEMM3: scores[b] = hp_b * sp_b^T (f32, overlays dead input-split region)
    gemm_bt<1,1,0,0><<<dim3(8, 8, 16), blk, 0, stream>>>(
        hp_hi, hp_lo, sp_hi, sp_lo, nullptr, sc, nullptr, nullptr, nullptr,
        1024, 1024, 1024, 1024, 1048576L, 1048576L, 1048576L, 1024);

    // softmax over j, bf16 probs written in place (row stride 2048 ushorts)
    softmax_inplace<<<16384, 256, 0, stream>>>(sc);

    // GEMM4: out[b] = probs_b * hpT_b^T (f32 -> d_out)
    gemm_bt<0,1,0,0><<<dim3(8, 8, 16), blk, 0, stream>>>(
        (const unsigned short*)sc, nullptr, hpT, nullptr, nullptr, (float*)d_out, nullptr, nullptr, nullptr,
        1024, 2048, 1024, 1024, 2097152L, 1048576L, 1048576L, 1024);
}

// Round 3
// 284.288 us; speedup vs baseline: 1.7395x; 1.7395x over previous
//
#include <hip/hip_runtime.h>
#include <hip/hip_bf16.h>
#include <stdint.h>

// B=16, TH=TS=HS=WS=1024
// res[b,i,o] = sum_j softmax_j(hp[b,i,:].sp[b,j,:]) * hp[b,j,o]
// hp = h*Wh^T + bh ; sp = s*Ws^T + bs
// Precision: fp16 inputs everywhere (8x lower rounding than bf16), f32 MFMA accum.

typedef _Float16 half_t;
typedef __attribute__((ext_vector_type(8))) _Float16 half8;   // 8 f16 (4 VGPR)
typedef __attribute__((ext_vector_type(4))) _Float16 half4;
typedef __attribute__((ext_vector_type(4))) float floatx4;    // MFMA acc

__device__ __forceinline__ void gl2lds16(const void* g, void* l) {
    __builtin_amdgcn_global_load_lds(
        (const __attribute__((address_space(1))) uint32_t*)(uintptr_t)g,
        (__attribute__((address_space(3))) uint32_t*)(uintptr_t)l,
        16, 0, 0);
}

#define TILE 128
#define BK 32

// C[r][c] = sum_k A[r][k]*B[c][k] (+bias[c]); operands K-major (B^T GEMM), fp16.
// Outputs: WF32 -> f32 Cf (ldcf); WH16 -> fp16 Ch (ld=N); WH16T -> fp16
// transposed per-1024-row batch (for PV's B operand).
template<int WF32, int WH16, int WH16T>
__global__ void gemm_bt(const half_t* __restrict__ A,
                        const half_t* __restrict__ B,
                        const float* __restrict__ bias,
                        float* __restrict__ Cf,
                        half_t* __restrict__ Ch,
                        half_t* __restrict__ ChT,
                        int K, int lda, int ldb, int N,
                        long aBatch, long bBatch, long cfBatch,
                        int ldcf)
{
    __shared__ __attribute__((aligned(16))) half_t At[2][TILE * BK];
    __shared__ __attribute__((aligned(16))) half_t Bt[2][TILE * BK];

    const int tid  = threadIdx.x;
    const int wave = tid >> 6;
    const int lane = tid & 63;
    const int wr = wave >> 1, wc = wave & 1;       // wave -> 64x64 quadrant
    const int lg = lane >> 4, lr = lane & 15;      // k-group / row-in-16

    const long batch = blockIdx.z;
    const half_t* Ab = A + batch * aBatch;
    const half_t* Bb = B + batch * bBatch;
    const int row0 = blockIdx.x * TILE;
    const int col0 = blockIdx.y * TILE;

    floatx4 acc[4][4];
#pragma unroll
    for (int m = 0; m < 4; ++m)
#pragma unroll
        for (int n = 0; n < 4; ++n)
            acc[m][n] = (floatx4){0.f, 0.f, 0.f, 0.f};

    const int NT = K / BK;

    auto stage = [&](int buf, int kk) {
        // tile: 128 rows x 32 f16 = 8192B; 256 thr x 16B x 2 issues per operand
#pragma unroll
        for (int i = 0; i < 2; ++i) {
            const int o = i * 4096 + tid * 16;     // linear byte off in 8KB tile
            const int row = o >> 6;                // 64B per row (32 f16)
            const int colb = o & 63;
            gl2lds16((const char*)Ab + (long)(row0 + row) * ((long)lda * 2) + (long)kk * 2 + colb,
                     (char*)&At[buf][0] + i * 4096 + wave * 1024);
        }
#pragma unroll
        for (int i = 0; i < 2; ++i) {
            const int o = i * 4096 + tid * 16;
            const int row = o >> 6;
            const int colb = o & 63;
            gl2lds16((const char*)Bb + (long)(col0 + row) * ((long)ldb * 2) + (long)kk * 2 + colb,
                     (char*)&Bt[buf][0] + i * 4096 + wave * 1024);
        }
    };

    stage(0, 0);
    int cur = 0;
    for (int kt = 0; kt < NT; ++kt) {
        __syncthreads();                            // buf[cur] ready (drains vmcnt)
        if (kt + 1 < NT) stage(cur ^ 1, (kt + 1) * BK);

        half8 af[4], bfr[4];
#pragma unroll
        for (int m = 0; m < 4; ++m) {
            const int r = wr * 64 + m * 16 + lr;
            af[m] = *(const half8*)&At[cur][r * BK + lg * 8];
        }
#pragma unroll
        for (int n = 0; n < 4; ++n) {
            const int c = wc * 64 + n * 16 + lr;
            bfr[n] = *(const half8*)&Bt[cur][c * BK + lg * 8];
        }
#pragma unroll
        for (int m = 0; m < 4; ++m)
#pragma unroll
            for (int n = 0; n < 4; ++n)
                acc[m][n] = __builtin_amdgcn_mfma_f32_16x16x32_f16(af[m], bfr[n], acc[m][n], 0, 0, 0);
        cur ^= 1;
    }

    // epilogue: D frag layout col=lane&15, row=(lane>>4)*4+j
#pragma unroll
    for (int m = 0; m < 4; ++m) {
        const int gr0 = row0 + wr * 64 + m * 16 + lg * 4;
#pragma unroll
        for (int n = 0; n < 4; ++n) {
            const int gc = col0 + wc * 64 + n * 16 + lr;
            floatx4 v = acc[m][n];
            if (bias) {
                const float b = bias[gc];
                v[0] += b; v[1] += b; v[2] += b; v[3] += b;
            }
            if (WF32) {
                float* p = Cf + batch * cfBatch + (long)gr0 * ldcf + gc;
#pragma unroll
                for (int j = 0; j < 4; ++j) p[(long)j * ldcf] = v[j];
            }
            if (WH16) {
#pragma unroll
                for (int j = 0; j < 4; ++j)
                    Ch[(long)(gr0 + j) * N + gc] = (half_t)v[j];
            }
            if (WH16T) {
                // hpT[b2][col][t], b2 = global_row/1024 ; 4 consecutive t -> 8B store
                const int b2 = gr0 >> 10;
                const int t  = gr0 & 1023;
                half4 pk = { (half_t)v[0], (half_t)v[1], (half_t)v[2], (half_t)v[3] };
                *(half4*)&ChT[(long)b2 * 1048576 + (long)gc * 1024 + t] = pk;
            }
        }
    }
}

// In-place: reads f32 row (1024), writes fp16 probabilities over its own first half.
// Safe: all reads happen before the first __syncthreads, all writes after the last.
__global__ void softmax_inplace(float* __restrict__ S) {
    const long r = blockIdx.x;
    float* row = S + r * 1024;
    const int tid = threadIdx.x;
    const int wave = tid >> 6, lane = tid & 63;

    float4 v = ((const float4*)row)[tid];
    float mx = fmaxf(fmaxf(v.x, v.y), fmaxf(v.z, v.w));
#pragma unroll
    for (int off = 32; off > 0; off >>= 1)
        mx = fmaxf(mx, __shfl_xor(mx, off));
    __shared__ float rmx[4], rsm[4];
    if (lane == 0) rmx[wave] = mx;
    __syncthreads();
    mx = fmaxf(fmaxf(rmx[0], rmx[1]), fmaxf(rmx[2], rmx[3]));

    float e0 = __expf(v.x - mx), e1 = __expf(v.y - mx);
    float e2 = __expf(v.z - mx), e3 = __expf(v.w - mx);
    float s = e0 + e1 + e2 + e3;
#pragma unroll
    for (int off = 32; off > 0; off >>= 1)
        s += __shfl_xor(s, off);
    if (lane == 0) rsm[wave] = s;
    __syncthreads();
    s = rsm[0] + rsm[1] + rsm[2] + rsm[3];

    const float inv = 1.0f / s;
    half4 o = { (half_t)(e0 * inv), (half_t)(e1 * inv), (half_t)(e2 * inv), (half_t)(e3 * inv) };
    ((half4*)((half_t*)S + r * 2048))[tid] = o;
}

__global__ void cvt_f16(const float4* __restrict__ src, half4* __restrict__ dst, int n4) {
    const int stride = gridDim.x * blockDim.x;
    for (int i = blockIdx.x * blockDim.x + threadIdx.x; i < n4; i += stride) {
        float4 v = src[i];
        half4 o = { (half_t)v.x, (half_t)v.y, (half_t)v.z, (half_t)v.w };
        dst[i] = o;
    }
}

extern "C" void kernel_launch(void* const* d_in, const int* in_sizes, int n_in,
                              void* d_out, int out_size, void* d_ws, size_t ws_size,
                              hipStream_t stream) {
    const float* h  = (const float*)d_in[0];
    const float* s  = (const float*)d_in[1];
    const float* Wh = (const float*)d_in[2];
    const float* bh = (const float*)d_in[3];
    const float* Ws = (const float*)d_in[4];
    const float* bs = (const float*)d_in[5];

    const long MB = 16384;   // B*TH
    const long D  = 1024;

    // workspace carve (~164 MB); h16/s16 region reused for f32 scores
    char* w = (char*)d_ws;
    half_t* h16 = (half_t*)w;  w += MB * D * 2;    // 32MB
    half_t* s16 = (half_t*)w;  w += MB * D * 2;    // 32MB
    float*  sc  = (float*)h16;                     // scores alias (64MB over h16+s16)
    half_t* Wh16 = (half_t*)w;  w += D * D * 2;
    half_t* Ws16 = (half_t*)w;  w += D * D * 2;
    half_t* hp16 = (half_t*)w;  w += MB * D * 2;   // [16384][1024]
    half_t* sp16 = (half_t*)w;  w += MB * D * 2;
    half_t* hpT  = (half_t*)w;  w += MB * D * 2;   // [16][o][t]

    dim3 blk(256);

    cvt_f16<<<512,  256, 0, stream>>>((const float4*)Wh, (half4*)Wh16, (int)(D * D / 4));
    cvt_f16<<<512,  256, 0, stream>>>((const float4*)Ws, (half4*)Ws16, (int)(D * D / 4));
    cvt_f16<<<2048, 256, 0, stream>>>((const float4*)h,  (half4*)h16,  (int)(MB * D / 4));
    cvt_f16<<<2048, 256, 0, stream>>>((const float4*)s,  (half4*)s16,  (int)(MB * D / 4));

    // GEMM1: hp = h*Wh^T + bh (fp16 + per-batch transpose)
    gemm_bt<0,1,1><<<dim3(128, 8, 1), blk, 0, stream>>>(
        h16, Wh16, bh, nullptr, hp16, hpT, 1024, 1024, 1024, 1024, 0, 0, 0, 0);
    // GEMM2: sp = s*Ws^T + bs (fp16)
    gemm_bt<0,1,0><<<dim3(128, 8, 1), blk, 0, stream>>>(
        s16, Ws16, bs, nullptr, sp16, nullptr, 1024, 1024, 1024, 1024, 0, 0, 0, 0);
    // GEMM3: scores[b] = hp_b * sp_b^T (f32, overlays dead h16/s16 region)
    gemm_bt<1,0,0><<<dim3(8, 8, 16), blk, 0, stream>>>(
        hp16, sp16, nullptr, sc, nullptr, nullptr, 1024, 1024, 1024, 1024,
        1048576L, 1048576L, 1048576L, 1024);
    // softmax over j, fp16 probs written in place (row stride 2048 halves)
    softmax_inplace<<<16384, 256, 0, stream>>>(sc);
    // GEMM4: out[b] = probs_b * hpT_b^T (f32 -> d_out)
    gemm_bt<1,0,0><<<dim3(8, 8, 16), blk, 0, stream>>>(
        (const half_t*)sc, hpT, nullptr, (float*)d_out, nullptr, nullptr,
        1024, 2048, 1024, 1024, 2097152L, 1048576L, 1048576L, 1024);
}

// Round 4
// 245.486 us; speedup vs baseline: 2.0144x; 1.1581x over previous
//
#include <hip/hip_runtime.h>
#include <hip/hip_bf16.h>
#include <stdint.h>

// B=16, TH=TS=HS=WS=1024
// res[b,i,o] = sum_j softmax_j(hp[b,i,:].sp[b,j,:]) * hp[b,j,o]
// hp = h*Wh^T + bh ; sp = s*Ws^T + bs
// fp16 operands, f32 MFMA accum. 256^2 8-phase GEMM (T2+T3+T4+T5).

typedef _Float16 half_t;
typedef __attribute__((ext_vector_type(8))) _Float16 half8;   // 4 VGPR
typedef __attribute__((ext_vector_type(4))) _Float16 half4;
typedef __attribute__((ext_vector_type(4))) float floatx4;

__device__ __forceinline__ void gl2lds16(const void* g, void* l) {
    __builtin_amdgcn_global_load_lds(
        (const __attribute__((address_space(1))) uint32_t*)(uintptr_t)g,
        (__attribute__((address_space(3))) uint32_t*)(uintptr_t)l,
        16, 0, 0);
}

#define PH_MID() do { asm volatile("" ::: "memory"); \
    __builtin_amdgcn_sched_barrier(0); \
    __builtin_amdgcn_s_barrier(); \
    asm volatile("s_waitcnt lgkmcnt(0)" ::: "memory"); \
    __builtin_amdgcn_sched_barrier(0); } while (0)

#define PH_END() do { asm volatile("" ::: "memory"); \
    __builtin_amdgcn_sched_barrier(0); \
    __builtin_amdgcn_s_barrier(); \
    __builtin_amdgcn_sched_barrier(0); } while (0)

#define QUAD(mq, nq) do { \
    __builtin_amdgcn_s_setprio(1); \
    _Pragma("unroll") for (int mi = 0; mi < 4; ++mi) \
    _Pragma("unroll") for (int ni = 0; ni < 2; ++ni) \
    _Pragma("unroll") for (int ks = 0; ks < 2; ++ks) \
        acc[(mq)*4+mi][(nq)*2+ni] = __builtin_amdgcn_mfma_f32_16x16x32_f16( \
            aF[mi][ks], bF[nq][ni][ks], acc[(mq)*4+mi][(nq)*2+ni], 0, 0, 0); \
    __builtin_amdgcn_s_setprio(0); } while (0)

#define NT16 16   // K = 1024, BK = 64

// C[r][c] = sum_k A[r][k]*B[c][k] (+bias[c]); operands K-major (B^T GEMM), fp16.
// 256x256 tile, 8 waves (2Mx4N), per-wave 128x64, double-buffered 128KB LDS,
// st_16x32 XOR swizzle (byte ^= ((byte>>9)&1)<<5) via pre-swizzled global src.
template<int WF32, int WH16, int WH16T>
__global__ __launch_bounds__(512, 2) void gemm256(
    const half_t* __restrict__ A, const half_t* __restrict__ B,
    const float* __restrict__ bias,
    float* __restrict__ Cf, half_t* __restrict__ Ch, half_t* __restrict__ ChT,
    int lda, int ldb, int N,
    long aBatch, long bBatch, long cfBatch, int ldcf)
{
    extern __shared__ char smem[];   // [2][ A:32KB | B:32KB ] = 128KB

    const int tid  = threadIdx.x;
    const int wave = tid >> 6;
    const int lane = tid & 63;
    const int wr = wave >> 2;        // 0..1 -> rows wr*128..+127
    const int wc = wave & 3;         // 0..3 -> cols wc*64..+63
    const int lr = lane & 15, lg = lane >> 4;

    const long batch = blockIdx.z;
    const half_t* Ab = A + batch * aBatch;
    const half_t* Bb = B + batch * bBatch;
    const int row0 = blockIdx.x * 256;
    const int col0 = blockIdx.y * 256;

    floatx4 acc[8][4];
#pragma unroll
    for (int m = 0; m < 8; ++m)
#pragma unroll
        for (int n = 0; n < 4; ++n)
            acc[m][n] = (floatx4){0.f, 0.f, 0.f, 0.f};

    // stage one 16KB half-tile (2 x gl2lds16 per thread), linear LDS dest,
    // inverse-swizzled global source (swizzle is an involution on bit5^bit9).
    auto stageHalf = [&](int buf, int isA, int half, int kk) {
#pragma unroll
        for (int i = 0; i < 2; ++i) {
            const int off = half * 16384 + i * 8192 + tid * 16;  // byte in 32KB tile
            const int e = off ^ (((off >> 9) & 1) << 5);         // linear element pos
            const int r  = e >> 7;                               // 128B per row
            const int cb = e & 127;
            const char* g = isA
                ? (const char*)Ab + (long)(row0 + r) * ((long)lda * 2) + (long)kk * 2 + cb
                : (const char*)Bb + (long)(col0 + r) * ((long)ldb * 2) + (long)kk * 2 + cb;
            gl2lds16(g, smem + buf * 65536 + (isA ? 0 : 32768)
                          + half * 16384 + i * 8192 + wave * 1024);
        }
    };
    auto ldA = [&](int buf, int mt, int ks) -> half8 {
        const int row = wr * 128 + mt * 16 + lr;
        const int kp = (ks * 64 + lg * 16) ^ (((row >> 2) & 1) << 5);
        return *(const half8*)(smem + buf * 65536 + row * 128 + kp);
    };
    auto ldB = [&](int buf, int nt, int ks) -> half8 {
        const int row = wc * 64 + nt * 16 + lr;
        const int kp = (ks * 64 + lg * 16) ^ (((row >> 2) & 1) << 5);
        return *(const half8*)(smem + buf * 65536 + 32768 + row * 128 + kp);
    };

    // ---- prologue: K0 fully, K1 B-halves; wait K0 resident (4 newest = K1 B0,B1)
    stageHalf(0, 0, 0, 0);   // B0 K0
    stageHalf(0, 0, 1, 0);   // B1 K0
    stageHalf(0, 1, 0, 0);   // A0 K0
    stageHalf(0, 1, 1, 0);   // A1 K0
    stageHalf(1, 0, 0, 64);  // B0 K1
    stageHalf(1, 0, 1, 64);  // B1 K1
    asm volatile("s_waitcnt vmcnt(4)" ::: "memory");
    __builtin_amdgcn_sched_barrier(0);
    __builtin_amdgcn_s_barrier();
    __builtin_amdgcn_sched_barrier(0);

    half8 aF[4][2];          // current A m-quadrant (4 m-tiles x 2 ksub)
    half8 bF[2][2][2];       // both B n-quadrants (persist q0->q3)

    for (int t = 0; t < NT16; ++t) {
        const int cur = t & 1;

        // ---- q0: quadrant (mq0,nq0); read aF(mq0)+bF[0]; stage A0(t+1)->buf^1
#pragma unroll
        for (int mi = 0; mi < 4; ++mi)
#pragma unroll
            for (int ks = 0; ks < 2; ++ks) aF[mi][ks] = ldA(cur, mi, ks);
#pragma unroll
        for (int ni = 0; ni < 2; ++ni)
#pragma unroll
            for (int ks = 0; ks < 2; ++ks) bF[0][ni][ks] = ldB(cur, ni, ks);
        if (t + 1 < NT16) stageHalf(cur ^ 1, 1, 0, (t + 1) * 64);
        PH_MID();
        QUAD(0, 0);
        PH_END();

        // ---- q1: (mq0,nq1); read bF[1]; stage A1(t+1)
#pragma unroll
        for (int ni = 0; ni < 2; ++ni)
#pragma unroll
            for (int ks = 0; ks < 2; ++ks) bF[1][ni][ks] = ldB(cur, 2 + ni, ks);
        if (t + 1 < NT16) stageHalf(cur ^ 1, 1, 1, (t + 1) * 64);
        PH_MID();
        QUAD(0, 1);
        PH_END();

        // ---- q2: (mq1,nq1); read aF(mq1); stage B0(t+2)->buf cur
#pragma unroll
        for (int mi = 0; mi < 4; ++mi)
#pragma unroll
            for (int ks = 0; ks < 2; ++ks) aF[mi][ks] = ldA(cur, 4 + mi, ks);
        if (t + 2 < NT16) stageHalf(cur, 0, 0, (t + 2) * 64);
        PH_MID();
        QUAD(1, 1);
        PH_END();

        // ---- q3: (mq1,nq0); no ds reads; stage B1(t+2); counted vmcnt gate
        if (t + 2 < NT16) {
            stageHalf(cur, 0, 1, (t + 2) * 64);
            asm volatile("s_waitcnt vmcnt(4)" ::: "memory");   // keep B0,B1(t+2) in flight
        } else {
            asm volatile("s_waitcnt vmcnt(0)" ::: "memory");   // tail drain
        }
        PH_MID();
        QUAD(1, 0);
        PH_END();
    }

    // ---- epilogue: D frag layout col=lane&15, row=(lane>>4)*4+j
#pragma unroll
    for (int m = 0; m < 8; ++m) {
        const int gr0 = row0 + wr * 128 + m * 16 + lg * 4;
#pragma unroll
        for (int n = 0; n < 4; ++n) {
            const int gc = col0 + wc * 64 + n * 16 + lr;
            floatx4 v = acc[m][n];
            if (bias) {
                const float b = bias[gc];
                v[0] += b; v[1] += b; v[2] += b; v[3] += b;
            }
            if (WF32) {
                float* p = Cf + batch * cfBatch + (long)gr0 * ldcf + gc;
#pragma unroll
                for (int j = 0; j < 4; ++j) p[(long)j * ldcf] = v[j];
            }
            if (WH16) {
#pragma unroll
                for (int j = 0; j < 4; ++j)
                    Ch[(long)(gr0 + j) * N + gc] = (half_t)v[j];
            }
            if (WH16T) {
                const int b2 = gr0 >> 10;
                const int t0 = gr0 & 1023;
                half4 pk = { (half_t)v[0], (half_t)v[1], (half_t)v[2], (half_t)v[3] };
                *(half4*)&ChT[(long)b2 * 1048576 + (long)gc * 1024 + t0] = pk;
            }
        }
    }
}

// In-place: reads f32 row (1024), writes fp16 probabilities over its own first half.
__global__ void softmax_inplace(float* __restrict__ S) {
    const long r = blockIdx.x;
    float* row = S + r * 1024;
    const int tid = threadIdx.x;
    const int wave = tid >> 6, lane = tid & 63;

    float4 v = ((const float4*)row)[tid];
    float mx = fmaxf(fmaxf(v.x, v.y), fmaxf(v.z, v.w));
#pragma unroll
    for (int off = 32; off > 0; off >>= 1)
        mx = fmaxf(mx, __shfl_xor(mx, off));
    __shared__ float rmx[4], rsm[4];
    if (lane == 0) rmx[wave] = mx;
    __syncthreads();
    mx = fmaxf(fmaxf(rmx[0], rmx[1]), fmaxf(rmx[2], rmx[3]));

    float e0 = __expf(v.x - mx), e1 = __expf(v.y - mx);
    float e2 = __expf(v.z - mx), e3 = __expf(v.w - mx);
    float s = e0 + e1 + e2 + e3;
#pragma unroll
    for (int off = 32; off > 0; off >>= 1)
        s += __shfl_xor(s, off);
    if (lane == 0) rsm[wave] = s;
    __syncthreads();
    s = rsm[0] + rsm[1] + rsm[2] + rsm[3];

    const float inv = 1.0f / s;
    half4 o = { (half_t)(e0 * inv), (half_t)(e1 * inv), (half_t)(e2 * inv), (half_t)(e3 * inv) };
    ((half4*)((half_t*)S + r * 2048))[tid] = o;
}

__global__ void cvt_f16(const float4* __restrict__ src, half4* __restrict__ dst, int n4) {
    const int stride = gridDim.x * blockDim.x;
    for (int i = blockIdx.x * blockDim.x + threadIdx.x; i < n4; i += stride) {
        float4 v = src[i];
        half4 o = { (half_t)v.x, (half_t)v.y, (half_t)v.z, (half_t)v.w };
        dst[i] = o;
    }
}

extern "C" void kernel_launch(void* const* d_in, const int* in_sizes, int n_in,
                              void* d_out, int out_size, void* d_ws, size_t ws_size,
                              hipStream_t stream) {
    const float* h  = (const float*)d_in[0];
    const float* s  = (const float*)d_in[1];
    const float* Wh = (const float*)d_in[2];
    const float* bh = (const float*)d_in[3];
    const float* Ws = (const float*)d_in[4];
    const float* bs = (const float*)d_in[5];

    const long MB = 16384;   // B*TH
    const long D  = 1024;

    // workspace carve (~164 MB); h16/s16 region reused for f32 scores
    char* w = (char*)d_ws;
    half_t* h16 = (half_t*)w;  w += MB * D * 2;    // 32MB
    half_t* s16 = (half_t*)w;  w += MB * D * 2;    // 32MB
    float*  sc  = (float*)h16;                     // scores alias (64MB over h16+s16)
    half_t* Wh16 = (half_t*)w;  w += D * D * 2;
    half_t* Ws16 = (half_t*)w;  w += D * D * 2;
    half_t* hp16 = (half_t*)w;  w += MB * D * 2;   // [16384][1024]
    half_t* sp16 = (half_t*)w;  w += MB * D * 2;
    half_t* hpT  = (half_t*)w;  w += MB * D * 2;   // [16][o][t]

    hipFuncSetAttribute(reinterpret_cast<const void*>(&gemm256<0,1,1>),
                        hipFuncAttributeMaxDynamicSharedMemorySize, 131072);
    hipFuncSetAttribute(reinterpret_cast<const void*>(&gemm256<0,1,0>),
                        hipFuncAttributeMaxDynamicSharedMemorySize, 131072);
    hipFuncSetAttribute(reinterpret_cast<const void*>(&gemm256<1,0,0>),
                        hipFuncAttributeMaxDynamicSharedMemorySize, 131072);

    cvt_f16<<<512,  256, 0, stream>>>((const float4*)Wh, (half4*)Wh16, (int)(D * D / 4));
    cvt_f16<<<512,  256, 0, stream>>>((const float4*)Ws, (half4*)Ws16, (int)(D * D / 4));
    cvt_f16<<<2048, 256, 0, stream>>>((const float4*)h,  (half4*)h16,  (int)(MB * D / 4));
    cvt_f16<<<2048, 256, 0, stream>>>((const float4*)s,  (half4*)s16,  (int)(MB * D / 4));

    // GEMM1: hp = h*Wh^T + bh (fp16 + per-batch transposed copy)
    gemm256<0,1,1><<<dim3(64, 4, 1), 512, 131072, stream>>>(
        h16, Wh16, bh, nullptr, hp16, hpT, 1024, 1024, 1024, 0, 0, 0, 0);
    // GEMM2: sp = s*Ws^T + bs (fp16)
    gemm256<0,1,0><<<dim3(64, 4, 1), 512, 131072, stream>>>(
        s16, Ws16, bs, nullptr, sp16, nullptr, 1024, 1024, 1024, 0, 0, 0, 0);
    // GEMM3: scores[b] = hp_b * sp_b^T (f32, overlays dead h16/s16 region)
    gemm256<1,0,0><<<dim3(4, 4, 16), 512, 131072, stream>>>(
        hp16, sp16, nullptr, sc, nullptr, nullptr, 1024, 1024, 1024,
        1048576L, 1048576L, 1048576L, 1024);
    // softmax over j, fp16 probs written in place (row stride 2048 halves)
    softmax_inplace<<<16384, 256, 0, stream>>>(sc);
    // GEMM4: out[b] = probs_b * hpT_b^T (f32 -> d_out)
    gemm256<1,0,0><<<dim3(4, 4, 16), 512, 131072, stream>>>(
        (const half_t*)sc, hpT, nullptr, (float*)d_out, nullptr, nullptr,
        2048, 1024, 1024, 2097152L, 1048576L, 1048576L, 1024);
}

// Round 5
// 237.458 us; speedup vs baseline: 2.0825x; 1.0338x over previous
//
#include <hip/hip_runtime.h>
#include <hip/hip_bf16.h>
#include <stdint.h>

// B=16, TH=TS=HS=WS=1024
// res[b,i,o] = sum_j softmax_j(hp[b,i,:].sp[b,j,:]) * hp[b,j,o]
// hp = h*Wh^T + bh ; sp = s*Ws^T + bs
// fp16 operands, f32 MFMA accum. 256^2 8-phase GEMM (T2-corrected swizzle+T3+T4+T5).

typedef _Float16 half_t;
typedef __attribute__((ext_vector_type(8))) _Float16 half8;   // 4 VGPR
typedef __attribute__((ext_vector_type(4))) _Float16 half4;
typedef __attribute__((ext_vector_type(4))) float floatx4;

__device__ __forceinline__ void gl2lds16(const void* g, void* l) {
    __builtin_amdgcn_global_load_lds(
        (const __attribute__((address_space(1))) uint32_t*)(uintptr_t)g,
        (__attribute__((address_space(3))) uint32_t*)(uintptr_t)l,
        16, 0, 0);
}

// barrier -> wait LDS data -> fence MFMA hoisting (rule #18); nothing else pinned
#define PH_MID() do { \
    __builtin_amdgcn_s_barrier(); \
    asm volatile("s_waitcnt lgkmcnt(0)" ::: "memory"); \
    __builtin_amdgcn_sched_barrier(0); } while (0)

#define PH_END() __builtin_amdgcn_s_barrier()

#define QUAD(mq, nq) do { \
    __builtin_amdgcn_s_setprio(1); \
    _Pragma("unroll") for (int mi = 0; mi < 4; ++mi) \
    _Pragma("unroll") for (int ni = 0; ni < 2; ++ni) \
    _Pragma("unroll") for (int ks = 0; ks < 2; ++ks) \
        acc[(mq)*4+mi][(nq)*2+ni] = __builtin_amdgcn_mfma_f32_16x16x32_f16( \
            aF[mi][ks], bF[nq][ni][ks], acc[(mq)*4+mi][(nq)*2+ni], 0, 0, 0); \
    __builtin_amdgcn_s_setprio(0); } while (0)

#define NT16 16   // K = 1024, BK = 64

// C[r][c] = sum_k A[r][k]*B[c][k] (+bias[c]); operands K-major (B^T GEMM), fp16.
// 256x256 tile, 8 waves (2Mx4N), per-wave 128x64, double-buffered 128KB LDS.
// Swizzle: rows are 128B (= 32 banks), so banks depend only on within-row
// offset; XOR byte bits 4-6 with row&7 spreads 8 rows over all 8 16B slots.
// Applied on BOTH sides: pre-swizzled global source (linear gl2lds dest) and
// swizzled ds_read offset (involution).
template<int WF32, int WH16, int WH16T>
__global__ __launch_bounds__(512, 2) void gemm256(
    const half_t* __restrict__ A, const half_t* __restrict__ B,
    const float* __restrict__ bias,
    float* __restrict__ Cf, half_t* __restrict__ Ch, half_t* __restrict__ ChT,
    int lda, int ldb, int N,
    long aBatch, long bBatch, long cfBatch, int ldcf)
{
    extern __shared__ char smem[];   // [2][ A:32KB | B:32KB ] = 128KB

    const int tid  = threadIdx.x;
    const int wave = tid >> 6;
    const int lane = tid & 63;
    const int wr = wave >> 2;        // 0..1 -> rows wr*128..+127
    const int wc = wave & 3;         // 0..3 -> cols wc*64..+63
    const int lr = lane & 15, lg = lane >> 4;

    const long batch = blockIdx.z;
    const half_t* Ab = A + batch * aBatch;
    const half_t* Bb = B + batch * bBatch;
    const int row0 = blockIdx.x * 256;
    const int col0 = blockIdx.y * 256;

    floatx4 acc[8][4];
#pragma unroll
    for (int m = 0; m < 8; ++m)
#pragma unroll
        for (int n = 0; n < 4; ++n)
            acc[m][n] = (floatx4){0.f, 0.f, 0.f, 0.f};

    // stage one 16KB half-tile (2 x gl2lds16/thread), linear LDS dest,
    // inverse-swizzled global source. off bits 7-9 = row&7; XOR into bits 4-6.
    auto stageHalf = [&](int buf, int isA, int half, int kk) {
#pragma unroll
        for (int i = 0; i < 2; ++i) {
            const int off = half * 16384 + i * 8192 + tid * 16;  // byte in 32KB tile
            const int e = off ^ (((off >> 7) & 7) << 4);         // linear element pos
            const int r  = e >> 7;                               // 128B per row
            const int cb = e & 127;
            const char* g = isA
                ? (const char*)Ab + (long)(row0 + r) * ((long)lda * 2) + (long)kk * 2 + cb
                : (const char*)Bb + (long)(col0 + r) * ((long)ldb * 2) + (long)kk * 2 + cb;
            gl2lds16(g, smem + buf * 65536 + (isA ? 0 : 32768)
                          + half * 16384 + i * 8192 + wave * 1024);
        }
    };
    auto ldA = [&](int buf, int mt, int ks) -> half8 {
        const int row = wr * 128 + mt * 16 + lr;                 // row&7 == lr&7
        const int kp = (ks * 64 + lg * 16) ^ ((row & 7) << 4);
        return *(const half8*)(smem + buf * 65536 + row * 128 + kp);
    };
    auto ldB = [&](int buf, int nt, int ks) -> half8 {
        const int row = wc * 64 + nt * 16 + lr;
        const int kp = (ks * 64 + lg * 16) ^ ((row & 7) << 4);
        return *(const half8*)(smem + buf * 65536 + 32768 + row * 128 + kp);
    };

    // ---- prologue: K0 fully, K1 B-halves; wait K0 resident (4 newest = K1 B0,B1)
    stageHalf(0, 0, 0, 0);   // B0 K0
    stageHalf(0, 0, 1, 0);   // B1 K0
    stageHalf(0, 1, 0, 0);   // A0 K0
    stageHalf(0, 1, 1, 0);   // A1 K0
    stageHalf(1, 0, 0, 64);  // B0 K1
    stageHalf(1, 0, 1, 64);  // B1 K1
    asm volatile("s_waitcnt vmcnt(4)" ::: "memory");
    __builtin_amdgcn_s_barrier();
    __builtin_amdgcn_sched_barrier(0);

    half8 aF[4][2];          // current A m-quadrant (4 m-tiles x 2 ksub)
    half8 bF[2][2][2];       // both B n-quadrants (persist q0->q3)

    for (int t = 0; t < NT16; ++t) {
        const int cur = t & 1;

        // ---- q0: quadrant (mq0,nq0); read aF(mq0)+bF[0]; stage A0(t+1)->buf^1
#pragma unroll
        for (int mi = 0; mi < 4; ++mi)
#pragma unroll
            for (int ks = 0; ks < 2; ++ks) aF[mi][ks] = ldA(cur, mi, ks);
#pragma unroll
        for (int ni = 0; ni < 2; ++ni)
#pragma unroll
            for (int ks = 0; ks < 2; ++ks) bF[0][ni][ks] = ldB(cur, ni, ks);
        if (t + 1 < NT16) stageHalf(cur ^ 1, 1, 0, (t + 1) * 64);
        PH_MID();
        QUAD(0, 0);
        PH_END();

        // ---- q1: (mq0,nq1); read bF[1]; stage A1(t+1)
#pragma unroll
        for (int ni = 0; ni < 2; ++ni)
#pragma unroll
            for (int ks = 0; ks < 2; ++ks) bF[1][ni][ks] = ldB(cur, 2 + ni, ks);
        if (t + 1 < NT16) stageHalf(cur ^ 1, 1, 1, (t + 1) * 64);
        PH_MID();
        QUAD(0, 1);
        PH_END();

        // ---- q2: (mq1,nq1); read aF(mq1); stage B0(t+2)->buf cur
#pragma unroll
        for (int mi = 0; mi < 4; ++mi)
#pragma unroll
            for (int ks = 0; ks < 2; ++ks) aF[mi][ks] = ldA(cur, 4 + mi, ks);
        if (t + 2 < NT16) stageHalf(cur, 0, 0, (t + 2) * 64);
        PH_MID();
        QUAD(1, 1);
        PH_END();

        // ---- q3: (mq1,nq0); no ds reads; stage B1(t+2); counted vmcnt gate
        if (t + 2 < NT16) {
            stageHalf(cur, 0, 1, (t + 2) * 64);
            asm volatile("s_waitcnt vmcnt(4)" ::: "memory");   // keep B0,B1(t+2) in flight
        } else {
            asm volatile("s_waitcnt vmcnt(0)" ::: "memory");   // tail drain
        }
        PH_MID();
        QUAD(1, 0);
        PH_END();
    }

    // ---- epilogue: D frag layout col=lane&15, row=(lane>>4)*4+j
#pragma unroll
    for (int m = 0; m < 8; ++m) {
        const int gr0 = row0 + wr * 128 + m * 16 + lg * 4;
#pragma unroll
        for (int n = 0; n < 4; ++n) {
            const int gc = col0 + wc * 64 + n * 16 + lr;
            floatx4 v = acc[m][n];
            if (bias) {
                const float b = bias[gc];
                v[0] += b; v[1] += b; v[2] += b; v[3] += b;
            }
            if (WF32) {
                float* p = Cf + batch * cfBatch + (long)gr0 * ldcf + gc;
#pragma unroll
                for (int j = 0; j < 4; ++j) p[(long)j * ldcf] = v[j];
            }
            if (WH16) {
#pragma unroll
                for (int j = 0; j < 4; ++j)
                    Ch[(long)(gr0 + j) * N + gc] = (half_t)v[j];
            }
            if (WH16T) {
                const int b2 = gr0 >> 10;
                const int t0 = gr0 & 1023;
                half4 pk = { (half_t)v[0], (half_t)v[1], (half_t)v[2], (half_t)v[3] };
                *(half4*)&ChT[(long)b2 * 1048576 + (long)gc * 1024 + t0] = pk;
            }
        }
    }
}

// In-place: reads f32 row (1024), writes fp16 probabilities over its own first half.
__global__ void softmax_inplace(float* __restrict__ S) {
    const long r = blockIdx.x;
    float* row = S + r * 1024;
    const int tid = threadIdx.x;
    const int wave = tid >> 6, lane = tid & 63;

    float4 v = ((const float4*)row)[tid];
    float mx = fmaxf(fmaxf(v.x, v.y), fmaxf(v.z, v.w));
#pragma unroll
    for (int off = 32; off > 0; off >>= 1)
        mx = fmaxf(mx, __shfl_xor(mx, off));
    __shared__ float rmx[4], rsm[4];
    if (lane == 0) rmx[wave] = mx;
    __syncthreads();
    mx = fmaxf(fmaxf(rmx[0], rmx[1]), fmaxf(rmx[2], rmx[3]));

    float e0 = __expf(v.x - mx), e1 = __expf(v.y - mx);
    float e2 = __expf(v.z - mx), e3 = __expf(v.w - mx);
    float s = e0 + e1 + e2 + e3;
#pragma unroll
    for (int off = 32; off > 0; off >>= 1)
        s += __shfl_xor(s, off);
    if (lane == 0) rsm[wave] = s;
    __syncthreads();
    s = rsm[0] + rsm[1] + rsm[2] + rsm[3];

    const float inv = 1.0f / s;
    half4 o = { (half_t)(e0 * inv), (half_t)(e1 * inv), (half_t)(e2 * inv), (half_t)(e3 * inv) };
    ((half4*)((half_t*)S + r * 2048))[tid] = o;
}

__global__ void cvt_f16(const float4* __restrict__ src, half4* __restrict__ dst, int n4) {
    const int stride = gridDim.x * blockDim.x;
    for (int i = blockIdx.x * blockDim.x + threadIdx.x; i < n4; i += stride) {
        float4 v = src[i];
        half4 o = { (half_t)v.x, (half_t)v.y, (half_t)v.z, (half_t)v.w };
        dst[i] = o;
    }
}

extern "C" void kernel_launch(void* const* d_in, const int* in_sizes, int n_in,
                              void* d_out, int out_size, void* d_ws, size_t ws_size,
                              hipStream_t stream) {
    const float* h  = (const float*)d_in[0];
    const float* s  = (const float*)d_in[1];
    const float* Wh = (const float*)d_in[2];
    const float* bh = (const float*)d_in[3];
    const float* Ws = (const float*)d_in[4];
    const float* bs = (const float*)d_in[5];

    const long MB = 16384;   // B*TH
    const long D  = 1024;

    // workspace carve (~164 MB); h16/s16 region reused for f32 scores
    char* w = (char*)d_ws;
    half_t* h16 = (half_t*)w;  w += MB * D * 2;    // 32MB
    half_t* s16 = (half_t*)w;  w += MB * D * 2;    // 32MB
    float*  sc  = (float*)h16;                     // scores alias (64MB over h16+s16)
    half_t* Wh16 = (half_t*)w;  w += D * D * 2;
    half_t* Ws16 = (half_t*)w;  w += D * D * 2;
    half_t* hp16 = (half_t*)w;  w += MB * D * 2;   // [16384][1024]
    half_t* sp16 = (half_t*)w;  w += MB * D * 2;
    half_t* hpT  = (half_t*)w;  w += MB * D * 2;   // [16][o][t]

    hipFuncSetAttribute(reinterpret_cast<const void*>(&gemm256<0,1,1>),
                        hipFuncAttributeMaxDynamicSharedMemorySize, 131072);
    hipFuncSetAttribute(reinterpret_cast<const void*>(&gemm256<0,1,0>),
                        hipFuncAttributeMaxDynamicSharedMemorySize, 131072);
    hipFuncSetAttribute(reinterpret_cast<const void*>(&gemm256<1,0,0>),
                        hipFuncAttributeMaxDynamicSharedMemorySize, 131072);

    cvt_f16<<<512,  256, 0, stream>>>((const float4*)Wh, (half4*)Wh16, (int)(D * D / 4));
    cvt_f16<<<512,  256, 0, stream>>>((const float4*)Ws, (half4*)Ws16, (int)(D * D / 4));
    cvt_f16<<<2048, 256, 0, stream>>>((const float4*)h,  (half4*)h16,  (int)(MB * D / 4));
    cvt_f16<<<2048, 256, 0, stream>>>((const float4*)s,  (half4*)s16,  (int)(MB * D / 4));

    // GEMM1: hp = h*Wh^T + bh (fp16 + per-batch transposed copy)
    gemm256<0,1,1><<<dim3(64, 4, 1), 512, 131072, stream>>>(
        h16, Wh16, bh, nullptr, hp16, hpT, 1024, 1024, 1024, 0, 0, 0, 0);
    // GEMM2: sp = s*Ws^T + bs (fp16)
    gemm256<0,1,0><<<dim3(64, 4, 1), 512, 131072, stream>>>(
        s16, Ws16, bs, nullptr, sp16, nullptr, 1024, 1024, 1024, 0, 0, 0, 0);
    // GEMM3: scores[b] = hp_b * sp_b^T (f32, overlays dead h16/s16 region)
    gemm256<1,0,0><<<dim3(4, 4, 16), 512, 131072, stream>>>(
        hp16, sp16, nullptr, sc, nullptr, nullptr, 1024, 1024, 1024,
        1048576L, 1048576L, 1048576L, 1024);
    // softmax over j, fp16 probs written in place (row stride 2048 halves)
    softmax_inplace<<<16384, 256, 0, stream>>>(sc);
    // GEMM4: out[b] = probs_b * hpT_b^T (f32 -> d_out)
    gemm256<1,0,0><<<dim3(4, 4, 16), 512, 131072, stream>>>(
        (const half_t*)sc, hpT, nullptr, (float*)d_out, nullptr, nullptr,
        2048, 1024, 1024, 2097152L, 1048576L, 1048576L, 1024);
}